// Round 13
// baseline (193.585 us; speedup 1.0000x reference)
//
#include <hip/hip_runtime.h>
#include <math.h>

#define A_DIM 60
#define NPATCH 625
#define SENT (1 << 20)

typedef short s16x8 __attribute__((ext_vector_type(8)));
typedef short s16x4 __attribute__((ext_vector_type(4)));
typedef float fx4   __attribute__((ext_vector_type(4)));
typedef float fx2   __attribute__((ext_vector_type(2)));

__device__ __forceinline__ short f2bf(float f) {
    unsigned u = __builtin_bit_cast(unsigned, f);
    unsigned r = (u + 0x7FFFu + ((u >> 16) & 1u)) >> 16;
    return (short)r;
}

// HW packed f32->bf16 (RNE). dst.lo = bf16(lo), dst.hi = bf16(hi). [T12]
__device__ __forceinline__ unsigned cvt_pk_bf16(float lo, float hi) {
    unsigned r;
    asm("v_cvt_pk_bf16_f32 %0, %1, %2" : "=v"(r) : "v"(lo), "v"(hi));
    return r;
}

// x mod 5 for x in [0,10)
__device__ __forceinline__ int md5(int x) { return (x >= 5) ? (x - 5) : x; }

// lgkm-only workgroup barrier: global prefetches stay in flight across it.
__device__ __forceinline__ void wg_barrier() {
    asm volatile("s_waitcnt lgkmcnt(0)" ::: "memory");
    __builtin_amdgcn_s_barrier();
    asm volatile("" ::: "memory");
}

// ---------------------------------------------------------------------------
// Prep: blocks 0..624 -> window bases + compaction + zero inactive patches;
// 625..696 -> w2 A-pack; 697 -> w3 A-pack + w1 oc-pair pack (float2).
// ---------------------------------------------------------------------------
__global__ __launch_bounds__(256) void k_prep(const int* __restrict__ masks,
                                              const float* __restrict__ w1,
                                              const float* __restrict__ w2,
                                              const float* __restrict__ w3,
                                              int* __restrict__ win,
                                              short* __restrict__ w2a,
                                              short* __restrict__ w3a,
                                              float* __restrict__ w1p,
                                              float* __restrict__ patches,
                                              int* __restrict__ actCnt,
                                              int* __restrict__ actList)
{
    const int blk = blockIdx.x, tid = threadIdx.x;
    if (blk < NPATCH) {
        __shared__ int s_f[60][4];
        __shared__ int s_row[64];
        int r = tid >> 2, q = tid & 3;
        if (r < 60) {
            const int4* m4 = (const int4*)(masks + (blk * 60 + r) * 128 + q * 32);
            int first = SENT;
#pragma unroll
            for (int j = 0; j < 8; ++j) {
                int4 v = m4[j];
                int base = q * 32 + j * 4;
                if (v.w) first = min(first, base + 3);
                if (v.z) first = min(first, base + 2);
                if (v.y) first = min(first, base + 1);
                if (v.x) first = min(first, base);
            }
            s_f[r][q] = first;
        }
        __syncthreads();
        if (tid < 60)
            s_row[tid] = min(min(s_f[tid][0], s_f[tid][1]),
                             min(s_f[tid][2], s_f[tid][3]));
        __syncthreads();
        int bact = 0;
        if (tid < 60) {
            int lo = SENT;
            for (int d = -3; d <= 3; ++d) {
                int rr = tid + d;
                if (rr >= 0 && rr < 60) lo = min(lo, s_row[rr]);
            }
            int b;
            if (lo >= SENT) b = SENT;
            else { b = lo - 3; if (b < 0) b = 0; if (b > 96) b = 96; }
            win[blk * 64 + tid] = b;
            bact = (b < 128) ? 1 : 0;
        }
        int cnt = __syncthreads_count(bact);
        if (cnt == 0) {
            if (tid < 50) patches[blk * 50 + tid] = 0.f;
        } else if (tid == 0) {
            int idx = atomicAdd(actCnt, 1);
            actList[idx] = blk;
        }
    } else if (blk < 697) {
        int i = (blk - NPATCH) * 256 + tid;     // < 18432
        int ic = i & 31, ol = (i >> 5) & 15, b2i = i >> 9;
        int ks = b2i % 9, T = b2i / 9;
        int oc = T * 16 + ol, dy = ks / 3, dxx = ks % 3;
        w2a[i] = f2bf(w2[((oc * 32 + ic) * 3 + dy) * 3 + dxx]);
    } else {
#pragma unroll
        for (int jj = 0; jj < 4; ++jj) {
            int i = jj * 256 + tid;             // < 1024
            int k = i & 31, m = (i >> 5) & 15, s = i >> 9;
            int dy = m / 3, dxx = m % 3;
            float v = (m < 9) ? w3[((s * 32 + k) * 3 + dy) * 3 + dxx] : 0.f;
            w3a[i] = f2bf(v);
        }
        // w1 oc-pair pack: pair gp covers ocs (2gp, 2gp+1)
        if (tid < 144) {
            int j = tid % 9, gp = tid / 9;
            float2 wv;
            wv.x = w1[(2 * gp) * 9 + j];
            wv.y = w1[(2 * gp + 1) * 9 + j];
            ((float2*)w1p)[gp * 9 + j] = wv;
        }
    }
}

// ---------------------------------------------------------------------------
// Main pipeline — R12 + R13: CONV2 2-way oc-split.
// R12 counters: VALUBusy 44->36.6% with flat duration => no longer
// issue-bound; LDS unit (~70-80% busy: 144 redundant wave-b128 conv2 reads
// + 21% conflict cycles) is the new binding pipe. Fix: wave roles
// (rvw=grp&1 row, ohw=grp>>1 oc-half-of-32). Each wave: afrag2[9][2]
// (72 VGPR, keeps 16x16 shape + 4 fx4 acc -- NOT R3/R5's 32x32 blowup),
// B-reads 36->18 per wave (72/block-iter, 2x cut). MFMA count unchanged.
// Bias added transiently at pack (R5-proven, no persistent regs). Validity
// de-masking: R12's garbage-never-consumed argument, verbatim.
// __launch_bounds__(256) plain: avoid (256,4) spill cliff; occupancy
// already 2.65 blocks/CU so a 3-block cap costs nothing (R4).
// ---------------------------------------------------------------------------
__global__ __launch_bounds__(256) void k_pipeline(
    const float* __restrict__ sino,
    const float* __restrict__ w1p, const float* __restrict__ b1,
    const short* __restrict__ w2a, const float* __restrict__ b2w,
    const short* __restrict__ w3a, const float* __restrict__ b3,
    const float* __restrict__ linw,
    const int* __restrict__ masks, const int* __restrict__ win,
    const int* __restrict__ actCnt, const int* __restrict__ actList,
    float* __restrict__ patches)
{
    __shared__ float s_in[5][38];                      // data 3..34 + sentinels
    __shared__ __align__(16) short s_x1[5][38 * 40];   // ring 5, sentinel cols
    __shared__ __align__(16) short s_x2[2][32 * 72];   // single pair buffer
    __shared__ float s_D[5][9][38];                    // conv3 ring, sentinels
    __shared__ __align__(16) float s_out3[2][2][32];   // dbl-buffer pairs
    __shared__ float s_lin[200];
    __shared__ int   s_base[64];
    __shared__ __align__(8) int s_db[61][2];           // raw deltas dy0, dy2

    const int tid = threadIdx.x;

    // compacted remap: uniform scalar loads, no barrier needed
    const int cnt = actCnt[0];
    const int pi  = (int)blockIdx.x >> 1;
    if (pi >= cnt) return;
    const int p    = actList[pi];
    const int half = (int)blockIdx.x & 1;
    const int pbo  = 2 * p + half;                     // output patch index

    const int S     = half ? 27 : 0;
    const int in_hi = half ? 59 : 32;
    const int x1lo  = half ? 28 : 0,  x1hi = half ? 59 : 31;
    const int x2lo  = half ? 29 : 0,  x2hi = half ? 59 : 30;
    const int olo   = half ? 30 : 0,  ohi  = half ? 59 : 29;
    const int F     = half ? 23 : 21;                  // depth-6 pipeline

    if (tid < 64)
        s_base[tid] = (tid >= 2 && tid < 62) ? win[p * 64 + (tid - 2)] : SENT;
    // zero sentinels: s_in cols {0,1,2,35,36,37} x 5 slots
    if (tid < 30) {
        int sl = tid / 6, c6 = tid % 6;
        s_in[sl][c6 < 3 ? c6 : 32 + c6] = 0.f;
    }
    // zero sentinels: s_x1 6 cols x 5 slots x 40 shorts = 150 uint4
    if (tid < 150) {
        int sl = tid / 30, rem = tid % 30;
        int c6 = rem / 5, q = rem % 5;
        int colz = (c6 < 3) ? c6 : 32 + c6;
        uint4 z; z.x = 0; z.y = 0; z.z = 0; z.w = 0;
        *(uint4*)&s_x1[sl][colz * 40 + q * 8] = z;
    }
    // zero sentinels: s_D cols {0,1,2,35,36,37} x 5 slots x 9 taps = 270
    for (int z = tid; z < 270; z += 256) {
        int sl = z / 54, rem = z - sl * 54;
        int mr = rem / 6, c6 = rem - mr * 6;
        s_D[sl][mr][c6 < 3 ? c6 : 32 + c6] = 0.f;
    }

    const int lane   = tid & 63;
    const int n      = lane & 15;
    const int quad   = lane >> 4;
    const int col    = tid & 31;
    const int rowsub = (tid >> 5) & 1;
    const int grp    = __builtin_amdgcn_readfirstlane(tid >> 6);  // 0..3
    const int rvw    = grp & 1;                        // conv2 wave row
    const int ohw    = grp >> 1;                       // conv2 wave oc-half

    // hoisted invariants: conv2 A-frags for 2 oc-blocks (oc 32*ohw..+31)
    s16x8 afrag2[9][2];
#pragma unroll
    for (int ks = 0; ks < 9; ++ks)
#pragma unroll
        for (int ocb = 0; ocb < 2; ++ocb)
            afrag2[ks][ocb] = *(const s16x8*)(w2a
                + ((((ohw * 2 + ocb) * 9 + ks)) << 9) + (n << 5) + (quad << 3));
    const s16x8 w3f0 = *(const s16x8*)(w3a + (n << 5) + (quad << 3));
    const s16x8 w3f1 = *(const s16x8*)(w3a + ((16 + n) << 5) + (quad << 3));
    const float b3s = b3[0];

    const int lk = tid >> 3;
    const int lg = tid & 7;
    float lacc = 0.f;
    float pwv[2][4] = {{0.f,0.f,0.f,0.f},{0.f,0.f,0.f,0.f}};
    float pv = 0.f; int pm = 0;
    int m5 = half ? 2 : 0;                             // (S+2f)%5, f=0

    wg_barrier();   // s_base / sentinels visible

    // raw window deltas (consumers start >=2 barriers later)
    if (tid < 61) {
        int bC = s_base[tid + 2];
        s_db[tid][0] = bC - s_base[tid + 1] - 1;
        s_db[tid][1] = bC - s_base[tid + 3] - 1;
    }

    // pre-loop input prefetch (pair 0)
    if (tid < 64) {
        int r = S + (tid >> 5);
        int b = s_base[r + 2];
        if (r <= in_hi && b < 128) {
            int t = b + col;
            pm = masks[(p * A_DIM + r) * 128 + t];
            pv = sino[r * 128 + t];
        }
    }

    for (int f = 0; f < F; ++f) {
        // ===================== G1 =====================
        // IN(f): commit prefetched pair f; prefetch pair f+1
        if (tid < 64) {
            int r = S + 2 * f + (tid >> 5);
            int b = s_base[r + 2];
            if (r <= in_hi && b < 128)
                s_in[md5(m5 + (tid >> 5))][col + 3] = pm ? pv : 0.f;
            int r2 = r + 2;
            int b2i = s_base[r2 + 2];
            if (r2 <= in_hi && b2i < 128) {
                int t = b2i + col;
                pm = masks[(p * A_DIM + r2) * 128 + t];
                pv = sino[r2 * 128 + t];
            }
        }
        // LIN(f-6) consume + linw prefetch (f-5); contiguous 4lg..4lg+3
        {
            int q = f - 6;
            if (q >= 0 && tid < 200) {
#pragma unroll
                for (int rs = 0; rs < 2; ++rs) {
                    int r = S + 2 * q + rs;
                    if (r >= olo && r <= ohi) {
                        int b = s_base[r + 2];
                        if (b < 128) {
                            const float4 ov = *(const float4*)
                                &s_out3[(f + 1) & 1][rs][lg * 4];
                            float a = lacc;
                            a = fmaf(ov.x, pwv[rs][0], a);
                            a = fmaf(ov.y, pwv[rs][1], a);
                            a = fmaf(ov.z, pwv[rs][2], a);
                            a = fmaf(ov.w, pwv[rs][3], a);
                            lacc = a;
                        }
                    }
                }
            }
            int q2 = f - 5;
            if (q2 >= 0 && tid < 200) {
#pragma unroll
                for (int rs = 0; rs < 2; ++rs) {
                    int r = S + 2 * q2 + rs;
                    if (r >= olo && r <= ohi) {
                        int b = s_base[r + 2];
                        if (b < 128) {
                            const float* a = linw + lk * (A_DIM * 128)
                                           + r * 128 + b + 4 * lg;
                            pwv[rs][0] = a[0]; pwv[rs][1] = a[1];
                            pwv[rs][2] = a[2]; pwv[rs][3] = a[3];
                        }
                    }
                }
            }
        }
        // CONV2 MFMA on pair f-3: wave (rvw, ohw); B-reads shared 2x.
        {
            const int rp = S + 2 * (f - 3);
            const bool act2 = (f >= 3) && (rp <= x2hi) && (rp + 1 >= x2lo);
            if (act2) {
                const int rw = rp + rvw;               // this wave's row
                const int2 dd = *(const int2*)&s_db[rw][0];
                const int slotA = md5(m5 + 3 + rvw);   // row rw-1
                const int slotB = md5(m5 + 4 + rvw);   // row rw
                const int slotC = md5(m5 + rvw);       // row rw+1

                fx4 acc[4];                            // [ocb][th] flat
#pragma unroll
                for (int t = 0; t < 4; ++t) {
                    acc[t][0] = 0.f; acc[t][1] = 0.f;
                    acc[t][2] = 0.f; acc[t][3] = 0.f;
                }

#pragma unroll
                for (int dy = 0; dy < 3; ++dy) {
                    const int slot = (dy == 0) ? slotA : (dy == 1 ? slotB : slotC);
                    const int d    = (dy == 0) ? dd.x : (dy == 1 ? -1 : dd.y);
#pragma unroll
                    for (int th = 0; th < 2; ++th) {
                        int j;
                        if (dy == 1) j = (th << 4) + n + 2;           // no clamp
                        else         j = min(max((th << 4) + n + d + 3, 0), 35);
                        const short* bp = &s_x1[slot][j * 40 + (quad << 3)];
                        s16x8 bf0 = *(const s16x8*)bp;
                        s16x8 bf1 = *(const s16x8*)(bp + 40);  // +80B
                        s16x8 bf2 = *(const s16x8*)(bp + 80);  // +160B
#pragma unroll
                        for (int ocb = 0; ocb < 2; ++ocb) {
                            int t = (ocb << 1) | th;
                            acc[t] = __builtin_amdgcn_mfma_f32_16x16x32_bf16(
                                         afrag2[dy * 3 + 0][ocb], bf0, acc[t], 0, 0, 0);
                            acc[t] = __builtin_amdgcn_mfma_f32_16x16x32_bf16(
                                         afrag2[dy * 3 + 1][ocb], bf1, acc[t], 0, 0, 0);
                            acc[t] = __builtin_amdgcn_mfma_f32_16x16x32_bf16(
                                         afrag2[dy * 3 + 2][ocb], bf2, acc[t], 0, 0, 0);
                        }
                    }
                }
                // pack + write; bias transient (no persistent regs)
#pragma unroll
                for (int t = 0; t < 4; ++t) {
                    int ocb = t >> 1, th = t & 1;
                    int obi = (ohw << 1) | ocb;
                    const float4 bb = *(const float4*)(b2w + (obi << 4) + (quad << 2));
                    unsigned plo = cvt_pk_bf16(fmaxf(acc[t][0] + bb.x, 0.f),
                                               fmaxf(acc[t][1] + bb.y, 0.f));
                    unsigned phi = cvt_pk_bf16(fmaxf(acc[t][2] + bb.z, 0.f),
                                               fmaxf(acc[t][3] + bb.w, 0.f));
                    uint2 pw; pw.x = plo; pw.y = phi;
                    int colw = (th << 4) + n;
                    *(uint2*)&s_x2[rvw][colw * 72 + (obi << 4) + (quad << 2)] = pw;
                }
            }
        }
        // COMBINE pair f-5: s_db deltas, dy=1 unclamped
        {
            const int rp5 = S + 2 * (f - 5);
            const bool act5 = (f >= 5) && (rp5 <= ohi) && (rp5 + 1 >= olo);
            if (act5 && tid < 64) {
                int rs = tid >> 5, c = tid & 31;
                int r = rp5 + rs;
                if (r >= olo && r <= ohi) {
                    int b = s_base[r + 2];
                    float o = 0.f;
                    if (b < 128) {
                        const int2 dd = *(const int2*)&s_db[r][0];
                        int yb = md5(m5 + 4 + rs);   // (r-1)%5 base
#pragma unroll
                        for (int dy = 0; dy < 3; ++dy) {
                            int j;
                            if (dy == 0)      j = min(max(c + dd.x + 3, 0), 35);
                            else if (dy == 1) j = c + 2;
                            else              j = min(max(c + dd.y + 3, 0), 35);
                            int ds = md5(yb + dy);
                            const float* Dp = &s_D[ds][dy * 3][0];
                            o += Dp[j] + Dp[38 + j + 1] + Dp[76 + j + 2];
                        }
                    }
                    s_out3[f & 1][rs][c] = o + b3s;
                }
            }
        }
        wg_barrier();

        // ===================== G2 =====================
        // CONV1 pair f-1: packed-pair fp32 (float2 oc pairs)
        {
            int r = S + 2 * (f - 1) + rowsub;
            if (f >= 1 && r >= x1lo && r <= x1hi) {
                int b = s_base[r + 2];
                if (b < 128) {
                    int x1b = m5 + rowsub;
                    int sl0 = md5(x1b + 2);   // (r+4)%5
                    int sl1 = md5(x1b + 3);   // r%5
                    int sl2 = md5(x1b + 4);   // (r+1)%5
                    const int2 dd = *(const int2*)&s_db[r][0];
                    float vin[9];
                    {
                        const float* r0 = &s_in[sl0][0];
                        const float* r1 = &s_in[sl1][0];
                        const float* r2 = &s_in[sl2][0];
                        int j0 = min(max(col + dd.x + 3, 0), 35);
                        int j2 = min(max(col + dd.y + 3, 0), 35);
                        vin[0] = r0[j0]; vin[1] = r0[j0 + 1]; vin[2] = r0[j0 + 2];
                        vin[3] = r1[col + 2]; vin[4] = r1[col + 3]; vin[5] = r1[col + 4];
                        vin[6] = r2[j2]; vin[7] = r2[j2 + 1]; vin[8] = r2[j2 + 2];
                    }
                    const fx2* wpp = (const fx2*)w1p + grp * 36;
                    fx2 ap0 = *(const fx2*)(b1 + grp * 8 + 0);
                    fx2 ap1 = *(const fx2*)(b1 + grp * 8 + 2);
                    fx2 ap2 = *(const fx2*)(b1 + grp * 8 + 4);
                    fx2 ap3 = *(const fx2*)(b1 + grp * 8 + 6);
#pragma unroll
                    for (int j = 0; j < 9; ++j) {
                        fx2 vv; vv[0] = vin[j]; vv[1] = vin[j];
                        ap0 = wpp[j]      * vv + ap0;
                        ap1 = wpp[9 + j]  * vv + ap1;
                        ap2 = wpp[18 + j] * vv + ap2;
                        ap3 = wpp[27 + j] * vv + ap3;
                    }
                    const fx2 z2 = {0.f, 0.f};
                    ap0 = __builtin_elementwise_max(ap0, z2);
                    ap1 = __builtin_elementwise_max(ap1, z2);
                    ap2 = __builtin_elementwise_max(ap2, z2);
                    ap3 = __builtin_elementwise_max(ap3, z2);
                    uint4 pk;
                    pk.x = cvt_pk_bf16(ap0[0], ap0[1]);
                    pk.y = cvt_pk_bf16(ap1[0], ap1[1]);
                    pk.z = cvt_pk_bf16(ap2[0], ap2[1]);
                    pk.w = cvt_pk_bf16(ap3[0], ap3[1]);
                    *(uint4*)&s_x1[sl1][(col + 3) * 40 + grp * 8] = pk;
                }
            }

            // CONV3 on pair f-3 (reads s_x2 written in G1(f))
            const int rp3 = S + 2 * (f - 3);
            const bool act3 = (f >= 3) && (rp3 <= x2hi) && (rp3 + 1 >= x2lo);
            if (act3) {
                int rv = grp & 1, nt = grp >> 1;
                const short* bp = &s_x2[rv][(nt * 16 + n) * 72 + (quad << 3)];
                s16x8 bf0 = *(const s16x8*)bp;
                s16x8 bf1 = *(const s16x8*)(bp + 32);
                fx4 a3 = {0.f, 0.f, 0.f, 0.f};
                a3 = __builtin_amdgcn_mfma_f32_16x16x32_bf16(w3f0, bf0, a3, 0, 0, 0);
                a3 = __builtin_amdgcn_mfma_f32_16x16x32_bf16(w3f1, bf1, a3, 0, 0, 0);
                int dslot = md5(m5 + 4 + rv);   // (rp3+rv)%5
#pragma unroll
                for (int e = 0; e < 4; ++e) {
                    int m = (quad << 2) + e;
                    if (m < 9) s_D[dslot][m][3 + nt * 16 + n] = a3[e];
                }
            }
        }
        wg_barrier();
        m5 = md5(m5 + 2);
    }

    if (tid < 200) s_lin[tid] = lacc;
    __syncthreads();
    if (tid < 25) {
        float s = 0.f;
#pragma unroll
        for (int g = 0; g < 8; ++g) s += s_lin[tid * 8 + g];
        patches[pbo * 25 + tid] = s;
    }
}

// ---------------------------------------------------------------------------
// k_img: blocks 0..63 compute y_hat once -> out[0..16383]; blocks 64..93
// zero the s_hat accumulation region.
// ---------------------------------------------------------------------------
__global__ __launch_bounds__(256) void k_img(const float* __restrict__ patches,
                                             const float* __restrict__ linb,
                                             float* __restrict__ out)
{
    const int blk = blockIdx.x, tid = threadIdx.x;
    if (blk < 64) {
        int i = blk * 256 + tid;            // < 16384
        int y = i >> 7, x = i & 127;
        float rec = 0.f;
        if (y < 125 && x < 125) {
            int pp = (y / 5) * 25 + (x / 5);
            int k  = (y % 5) * 5 + (x % 5);
            rec = patches[(2 * pp) * 25 + k] + patches[(2 * pp + 1) * 25 + k]
                + linb[k];
        }
        out[i] = 1.f / (1.f + expf(-rec));
    } else {
        int j = (blk - 64) * 256 + tid;     // < 7680
        if (j < A_DIM * 128) out[128 * 128 + j] = 0.f;
    }
}

// ---------------------------------------------------------------------------
// k_rad: 240 blocks = 60 angles x 4 s-chunks; y_hat L2-resident -> LDS via
// float4; fp32 atomicAdd partials into s_hat.
// ---------------------------------------------------------------------------
__global__ __launch_bounds__(256) void k_rad(const float* __restrict__ yimg,
                                             float* __restrict__ out)
{
    __shared__ float img[128 * 128];
    __shared__ float s_r[2][128];
    const int tid = threadIdx.x;
    const int a   = blockIdx.x >> 2;
    const int cch = blockIdx.x & 3;

#pragma unroll
    for (int j = 0; j < 16; ++j) {
        int idx = j * 256 + tid;            // float4 index < 4096
        ((float4*)img)[idx] = ((const float4*)yimg)[idx];
    }
    __syncthreads();

    const int t  = tid & 127;
    const int ss = tid >> 7;
    double ang = (double)a * (M_PI / 180.0);
    float ct = (float)cos(ang);
    float st = (float)sin(ang);
    const float c = 63.5f;
    float tt = (float)t - c;
    float sum = 0.f;
    int s0 = cch * 32 + ss * 16;
    for (int s = s0; s < s0 + 16; ++s) {
        float sv = (float)s - c;
        float x = c + tt * ct - sv * st;
        float y = c + tt * st + sv * ct;
        float fx = floorf(x), fy = floorf(y);
        int x0 = (int)fx, y0 = (int)fy;
        float wx = x - fx, wy = y - fy;
        bool vx0 = (x0 >= 0) & (x0 < 128), vx1 = (x0 + 1 >= 0) & (x0 + 1 < 128);
        bool vy0 = (y0 >= 0) & (y0 < 128), vy1 = (y0 + 1 >= 0) & (y0 + 1 < 128);
        int xc0 = min(max(x0, 0), 127), xc1 = min(max(x0 + 1, 0), 127);
        int yc0 = min(max(y0, 0), 127), yc1 = min(max(y0 + 1, 0), 127);
        float v00 = (vx0 & vy0) ? img[yc0 * 128 + xc0] : 0.f;
        float v10 = (vx1 & vy0) ? img[yc0 * 128 + xc1] : 0.f;
        float v01 = (vx0 & vy1) ? img[yc1 * 128 + xc0] : 0.f;
        float v11 = (vx1 & vy1) ? img[yc1 * 128 + xc1] : 0.f;
        sum += v00 * (1.f - wx) * (1.f - wy)
             + v10 * wx * (1.f - wy)
             + v01 * (1.f - wx) * wy
             + v11 * wx * wy;
    }
    s_r[ss][t] = sum;
    __syncthreads();
    if (ss == 0)
        atomicAdd(out + 128 * 128 + a * 128 + t, s_r[0][t] + s_r[1][t]);
}

// ---------------------------------------------------------------------------
extern "C" void kernel_launch(void* const* d_in, const int* in_sizes, int n_in,
                              void* d_out, int out_size, void* d_ws, size_t ws_size,
                              hipStream_t stream)
{
    (void)in_sizes; (void)n_in; (void)out_size; (void)ws_size;

    const float* sino  = (const float*)d_in[0];
    const float* w1    = (const float*)d_in[1];
    const float* b1    = (const float*)d_in[2];
    const float* w2    = (const float*)d_in[3];
    const float* b2    = (const float*)d_in[4];
    const float* w3    = (const float*)d_in[5];
    const float* b3    = (const float*)d_in[6];
    const float* lw    = (const float*)d_in[7];
    const float* lb    = (const float*)d_in[8];
    const int*   masks = (const int*)d_in[9];

    float* out = (float*)d_out;

    char* ws = (char*)d_ws;
    float* patches = (float*)ws;                        // 1250*25 fl = 125 KB
    int*   win     = (int*)(ws + 128 * 1024);           // 160 KB
    short* w2a     = (short*)(ws + 288 * 1024);         // 36 KB
    short* w3a     = (short*)(ws + 328 * 1024);         // 2 KB
    int*   actCnt  = (int*)(ws + 332 * 1024);           // 4 B
    int*   actList = (int*)(ws + 332 * 1024 + 64);      // 2.5 KB
    float* w1p     = (float*)(ws + 336 * 1024);         // 1.2 KB (oc pairs)

    hipMemsetAsync(actCnt, 0, sizeof(int), stream);
    k_prep<<<698, 256, 0, stream>>>(masks, w1, w2, w3, win, w2a, w3a, w1p,
                                    patches, actCnt, actList);
    k_pipeline<<<2 * NPATCH, 256, 0, stream>>>(sino, w1p, b1, w2a, b2, w3a, b3,
                                               lw, masks, win, actCnt, actList,
                                               patches);
    k_img<<<94, 256, 0, stream>>>(patches, lb, out);
    k_rad<<<4 * A_DIM, 256, 0, stream>>>(out, out);
}

// Round 14
// 166.798 us; speedup vs baseline: 1.1606x; 1.1606x over previous
//
#include <hip/hip_runtime.h>
#include <math.h>

#define A_DIM 60
#define NPATCH 625
#define SENT (1 << 20)

typedef short s16x8 __attribute__((ext_vector_type(8)));
typedef short s16x4 __attribute__((ext_vector_type(4)));
typedef float fx4   __attribute__((ext_vector_type(4)));
typedef float fx2   __attribute__((ext_vector_type(2)));

__device__ __forceinline__ short f2bf(float f) {
    unsigned u = __builtin_bit_cast(unsigned, f);
    unsigned r = (u + 0x7FFFu + ((u >> 16) & 1u)) >> 16;
    return (short)r;
}

// HW packed f32->bf16 (RNE). dst.lo = bf16(lo), dst.hi = bf16(hi). [T12]
__device__ __forceinline__ unsigned cvt_pk_bf16(float lo, float hi) {
    unsigned r;
    asm("v_cvt_pk_bf16_f32 %0, %1, %2" : "=v"(r) : "v"(lo), "v"(hi));
    return r;
}

// x mod 5 for x in [0,10)
__device__ __forceinline__ int md5(int x) { return (x >= 5) ? (x - 5) : x; }

// Closed-form active-patch predicate — EXACTLY _build_sinogram_masks's
// condition (d0<=c && d1<=c, c=64): both corner radii² <= 4096. Integer
// compare ≡ float-sqrt compare (all values <= 8192 exact in fp32, sqrt
// monotone). A patch is mask-active iff this holds; mask-active ⇒ every
// sino row has a nonzero (box projections are O(5) >> 1e-6) ⇒ win-active.
__device__ __forceinline__ int act_cf(int q) {
    int i = (q / 25) * 5, j = (q % 25) * 5;
    int a = (i - 64) * (i - 64) + (j - 64) * (j - 64);
    int b = (i - 59) * (i - 59) + (j - 59) * (j - 59);
    return (a <= 4096 && b <= 4096) ? 1 : 0;
}

// lgkm-only workgroup barrier: global prefetches stay in flight across it.
__device__ __forceinline__ void wg_barrier() {
    asm volatile("s_waitcnt lgkmcnt(0)" ::: "memory");
    __builtin_amdgcn_s_barrier();
    asm volatile("" ::: "memory");
}

// ---------------------------------------------------------------------------
// Prep: blocks 0..624 -> window bases + DETERMINISTIC compaction (closed-form
// rank via __syncthreads_count — no atomic, no memset) + zero inactive
// patches; 625..696 -> w2 A-pack; 697 -> w3 A-pack + w1 oc-pair pack +
// actCnt total.
// ---------------------------------------------------------------------------
__global__ __launch_bounds__(256) void k_prep(const int* __restrict__ masks,
                                              const float* __restrict__ w1,
                                              const float* __restrict__ w2,
                                              const float* __restrict__ w3,
                                              int* __restrict__ win,
                                              short* __restrict__ w2a,
                                              short* __restrict__ w3a,
                                              float* __restrict__ w1p,
                                              float* __restrict__ patches,
                                              int* __restrict__ actCnt,
                                              int* __restrict__ actList)
{
    const int blk = blockIdx.x, tid = threadIdx.x;
    if (blk < NPATCH) {
        __shared__ int s_f[60][4];
        __shared__ int s_row[64];
        int r = tid >> 2, q = tid & 3;
        if (r < 60) {
            const int4* m4 = (const int4*)(masks + (blk * 60 + r) * 128 + q * 32);
            int first = SENT;
#pragma unroll
            for (int j = 0; j < 8; ++j) {
                int4 v = m4[j];
                int base = q * 32 + j * 4;
                if (v.w) first = min(first, base + 3);
                if (v.z) first = min(first, base + 2);
                if (v.y) first = min(first, base + 1);
                if (v.x) first = min(first, base);
            }
            s_f[r][q] = first;
        }
        __syncthreads();
        if (tid < 60)
            s_row[tid] = min(min(s_f[tid][0], s_f[tid][1]),
                             min(s_f[tid][2], s_f[tid][3]));
        __syncthreads();
        int bact = 0;
        if (tid < 60) {
            int lo = SENT;
            for (int d = -3; d <= 3; ++d) {
                int rr = tid + d;
                if (rr >= 0 && rr < 60) lo = min(lo, s_row[rr]);
            }
            int b;
            if (lo >= SENT) b = SENT;
            else { b = lo - 3; if (b < 0) b = 0; if (b > 96) b = 96; }
            win[blk * 64 + tid] = b;
            bact = (b < 128) ? 1 : 0;
        }
        int cnt = __syncthreads_count(bact);
        // deterministic rank among closed-form-active patches with q < blk
        int rk = 0;
        rk += __syncthreads_count((tid < blk) ? act_cf(tid) : 0);
        rk += __syncthreads_count((256 + tid < blk) ? act_cf(256 + tid) : 0);
        rk += __syncthreads_count((512 + tid < blk) ? act_cf(512 + tid) : 0);
        if (cnt == 0) {
            if (tid < 50) patches[blk * 50 + tid] = 0.f;
        } else if (tid == 0) {
            actList[rk] = blk;
        }
    } else if (blk < 697) {
        int i = (blk - NPATCH) * 256 + tid;     // < 18432
        int ic = i & 31, ol = (i >> 5) & 15, b2i = i >> 9;
        int ks = b2i % 9, T = b2i / 9;
        int oc = T * 16 + ol, dy = ks / 3, dxx = ks % 3;
        w2a[i] = f2bf(w2[((oc * 32 + ic) * 3 + dy) * 3 + dxx]);
    } else {
#pragma unroll
        for (int jj = 0; jj < 4; ++jj) {
            int i = jj * 256 + tid;             // < 1024
            int k = i & 31, m = (i >> 5) & 15, s = i >> 9;
            int dy = m / 3, dxx = m % 3;
            float v = (m < 9) ? w3[((s * 32 + k) * 3 + dy) * 3 + dxx] : 0.f;
            w3a[i] = f2bf(v);
        }
        // w1 oc-pair pack: pair gp covers ocs (2gp, 2gp+1)
        if (tid < 144) {
            int j = tid % 9, gp = tid / 9;
            float2 wv;
            wv.x = w1[(2 * gp) * 9 + j];
            wv.y = w1[(2 * gp + 1) * 9 + j];
            ((float2*)w1p)[gp * 9 + j] = wv;
        }
        // total active count (closed-form; no atomic, no memset)
        int tot = 0;
        tot += __syncthreads_count(act_cf(tid));
        tot += __syncthreads_count(act_cf(256 + tid));
        tot += __syncthreads_count((512 + tid < NPATCH) ? act_cf(512 + tid) : 0);
        if (tid == 0) actCnt[0] = tot;
    }
}

// ---------------------------------------------------------------------------
// Main pipeline — R12 configuration (banked 78.5 us), verbatim.
// Design space brackets (R13 post-mortem): the kernel sits on the 64-VGPR/
// 8-wave occupancy cliff — any CONV2 redundancy-cut adds A-frag registers,
// crosses 64 VGPR, halves waves/SIMD, and loses more than the LDS-traffic
// cut gains (R3/R5/R13 all confirm). Instruction diet (R9-R11) exhausted
// the VALU side. This is the local optimum.
// ---------------------------------------------------------------------------
__global__ __launch_bounds__(256, 4) void k_pipeline(
    const float* __restrict__ sino,
    const float* __restrict__ w1p, const float* __restrict__ b1,
    const short* __restrict__ w2a, const float* __restrict__ b2w,
    const short* __restrict__ w3a, const float* __restrict__ b3,
    const float* __restrict__ linw,
    const int* __restrict__ masks, const int* __restrict__ win,
    const int* __restrict__ actCnt, const int* __restrict__ actList,
    float* __restrict__ patches)
{
    __shared__ float s_in[5][38];                      // data 3..34 + sentinels
    __shared__ __align__(16) short s_x1[5][38 * 40];   // ring 5, sentinel cols
    __shared__ __align__(16) short s_x2[2][32 * 72];   // single pair buffer
    __shared__ float s_D[5][9][38];                    // conv3 ring, sentinels
    __shared__ __align__(16) float s_out3[2][2][32];   // dbl-buffer pairs
    __shared__ float s_lin[200];
    __shared__ int   s_base[64];
    __shared__ __align__(8) int s_db[61][2];           // raw deltas dy0, dy2

    const int tid = threadIdx.x;

    // compacted remap: uniform scalar loads, no barrier needed
    const int cnt = actCnt[0];
    const int pi  = (int)blockIdx.x >> 1;
    if (pi >= cnt) return;
    const int p    = actList[pi];
    const int half = (int)blockIdx.x & 1;
    const int pbo  = 2 * p + half;                     // output patch index

    const int S     = half ? 27 : 0;
    const int in_hi = half ? 59 : 32;
    const int x1lo  = half ? 28 : 0,  x1hi = half ? 59 : 31;
    const int x2lo  = half ? 29 : 0,  x2hi = half ? 59 : 30;
    const int olo   = half ? 30 : 0,  ohi  = half ? 59 : 29;
    const int F     = half ? 23 : 21;                  // depth-6 pipeline

    if (tid < 64)
        s_base[tid] = (tid >= 2 && tid < 62) ? win[p * 64 + (tid - 2)] : SENT;
    // zero sentinels: s_in cols {0,1,2,35,36,37} x 5 slots
    if (tid < 30) {
        int sl = tid / 6, c6 = tid % 6;
        s_in[sl][c6 < 3 ? c6 : 32 + c6] = 0.f;
    }
    // zero sentinels: s_x1 6 cols x 5 slots x 40 shorts = 150 uint4
    if (tid < 150) {
        int sl = tid / 30, rem = tid % 30;
        int c6 = rem / 5, q = rem % 5;
        int colz = (c6 < 3) ? c6 : 32 + c6;
        uint4 z; z.x = 0; z.y = 0; z.z = 0; z.w = 0;
        *(uint4*)&s_x1[sl][colz * 40 + q * 8] = z;
    }
    // zero sentinels: s_D cols {0,1,2,35,36,37} x 5 slots x 9 taps = 270
    for (int z = tid; z < 270; z += 256) {
        int sl = z / 54, rem = z - sl * 54;
        int mr = rem / 6, c6 = rem - mr * 6;
        s_D[sl][mr][c6 < 3 ? c6 : 32 + c6] = 0.f;
    }

    const int lane   = tid & 63;
    const int n      = lane & 15;
    const int quad   = lane >> 4;
    const int col    = tid & 31;
    const int rowsub = (tid >> 5) & 1;
    const int grp    = __builtin_amdgcn_readfirstlane(tid >> 6);  // 0..3

    // hoisted invariants
    s16x8 afrag2[9];
#pragma unroll
    for (int ks = 0; ks < 9; ++ks)
        afrag2[ks] = *(const s16x8*)(w2a + (grp * 9 + ks) * 512 + (n << 5) + (quad << 3));
    const s16x8 w3f0 = *(const s16x8*)(w3a + (n << 5) + (quad << 3));
    const s16x8 w3f1 = *(const s16x8*)(w3a + ((16 + n) << 5) + (quad << 3));
    const float4 bv = *(const float4*)(b2w + (grp << 4) + (quad << 2));
    fx4 binit; binit[0] = bv.x; binit[1] = bv.y; binit[2] = bv.z; binit[3] = bv.w;
    const float b3s = b3[0];

    const int lk = tid >> 3;
    const int lg = tid & 7;
    float lacc = 0.f;
    float pwv[2][4] = {{0.f,0.f,0.f,0.f},{0.f,0.f,0.f,0.f}};
    float pv = 0.f; int pm = 0;
    int m5 = half ? 2 : 0;                             // (S+2f)%5, f=0

    wg_barrier();   // s_base / sentinels visible

    // raw window deltas (consumers start >=2 barriers later)
    if (tid < 61) {
        int bC = s_base[tid + 2];
        s_db[tid][0] = bC - s_base[tid + 1] - 1;
        s_db[tid][1] = bC - s_base[tid + 3] - 1;
    }

    // pre-loop input prefetch (pair 0)
    if (tid < 64) {
        int r = S + (tid >> 5);
        int b = s_base[r + 2];
        if (r <= in_hi && b < 128) {
            int t = b + col;
            pm = masks[(p * A_DIM + r) * 128 + t];
            pv = sino[r * 128 + t];
        }
    }

    for (int f = 0; f < F; ++f) {
        // ===================== G1 =====================
        // IN(f): commit prefetched pair f; prefetch pair f+1
        if (tid < 64) {
            int r = S + 2 * f + (tid >> 5);
            int b = s_base[r + 2];
            if (r <= in_hi && b < 128)
                s_in[md5(m5 + (tid >> 5))][col + 3] = pm ? pv : 0.f;
            int r2 = r + 2;
            int b2i = s_base[r2 + 2];
            if (r2 <= in_hi && b2i < 128) {
                int t = b2i + col;
                pm = masks[(p * A_DIM + r2) * 128 + t];
                pv = sino[r2 * 128 + t];
            }
        }
        // LIN(f-6) consume + linw prefetch (f-5); contiguous 4lg..4lg+3
        {
            int q = f - 6;
            if (q >= 0 && tid < 200) {
#pragma unroll
                for (int rs = 0; rs < 2; ++rs) {
                    int r = S + 2 * q + rs;
                    if (r >= olo && r <= ohi) {
                        int b = s_base[r + 2];
                        if (b < 128) {
                            const float4 ov = *(const float4*)
                                &s_out3[(f + 1) & 1][rs][lg * 4];
                            float a = lacc;
                            a = fmaf(ov.x, pwv[rs][0], a);
                            a = fmaf(ov.y, pwv[rs][1], a);
                            a = fmaf(ov.z, pwv[rs][2], a);
                            a = fmaf(ov.w, pwv[rs][3], a);
                            lacc = a;
                        }
                    }
                }
            }
            int q2 = f - 5;
            if (q2 >= 0 && tid < 200) {
#pragma unroll
                for (int rs = 0; rs < 2; ++rs) {
                    int r = S + 2 * q2 + rs;
                    if (r >= olo && r <= ohi) {
                        int b = s_base[r + 2];
                        if (b < 128) {
                            const float* a = linw + lk * (A_DIM * 128)
                                           + r * 128 + b + 4 * lg;
                            pwv[rs][0] = a[0]; pwv[rs][1] = a[1];
                            pwv[rs][2] = a[2]; pwv[rs][3] = a[3];
                        }
                    }
                }
            }
        }
        // CONV2 MFMA on pair f-3: s_db deltas, dy=1 unclamped fixed addr
        {
            const int rp = S + 2 * (f - 3);
            const bool act2 = (f >= 3) && (rp <= x2hi) && (rp + 1 >= x2lo);
            if (act2) {
                const int2 ddA = *(const int2*)&s_db[rp][0];
                const int2 ddB = *(const int2*)&s_db[rp + 1][0];
                int dbv[2][2];              // [dysel][rv]: dysel0=dy0, 1=dy2
                dbv[0][0] = ddA.x; dbv[0][1] = ddB.x;
                dbv[1][0] = ddA.y; dbv[1][1] = ddB.y;
                int slot[4];
                slot[0] = md5(m5 + 3);      // (rp+4)%5
                slot[1] = md5(m5 + 4);      // rp%5
                slot[2] = m5;               // (rp+1)%5
                slot[3] = md5(m5 + 1);      // (rp+2)%5

                fx4 acc[4];
#pragma unroll
                for (int t = 0; t < 4; ++t) acc[t] = binit;

#pragma unroll
                for (int dy = 0; dy < 3; ++dy) {
#pragma unroll
                    for (int t = 0; t < 4; ++t) {
                        int rv = t >> 1;
                        int j;
                        if (dy == 1) {
                            j = ((t & 1) << 4) + n + 2;       // no clamp
                        } else {
                            int idx0 = ((t & 1) << 4) + n
                                     + dbv[dy >> 1][rv];
                            j = min(max(idx0 + 3, 0), 35);    // v_med3_i32
                        }
                        const short* bp = &s_x1[slot[rv + dy]][j * 40 + (quad << 3)];
                        s16x8 bf0 = *(const s16x8*)bp;
                        s16x8 bf1 = *(const s16x8*)(bp + 40);  // offset:80
                        s16x8 bf2 = *(const s16x8*)(bp + 80);  // offset:160
                        acc[t] = __builtin_amdgcn_mfma_f32_16x16x32_bf16(
                                     afrag2[dy * 3 + 0], bf0, acc[t], 0, 0, 0);
                        acc[t] = __builtin_amdgcn_mfma_f32_16x16x32_bf16(
                                     afrag2[dy * 3 + 1], bf1, acc[t], 0, 0, 0);
                        acc[t] = __builtin_amdgcn_mfma_f32_16x16x32_bf16(
                                     afrag2[dy * 3 + 2], bf2, acc[t], 0, 0, 0);
                    }
                }
#pragma unroll
                for (int t = 0; t < 4; ++t) {
                    int rv = t >> 1;
                    int colw = ((t & 1) << 4) + n;
                    unsigned plo = cvt_pk_bf16(fmaxf(acc[t][0], 0.f),
                                               fmaxf(acc[t][1], 0.f));
                    unsigned phi = cvt_pk_bf16(fmaxf(acc[t][2], 0.f),
                                               fmaxf(acc[t][3], 0.f));
                    uint2 pw; pw.x = plo; pw.y = phi;
                    *(uint2*)&s_x2[rv][colw * 72 + (grp << 4) + (quad << 2)] = pw;
                }
            }
        }
        // COMBINE pair f-5: s_db deltas, dy=1 unclamped
        {
            const int rp5 = S + 2 * (f - 5);
            const bool act5 = (f >= 5) && (rp5 <= ohi) && (rp5 + 1 >= olo);
            if (act5 && tid < 64) {
                int rs = tid >> 5, c = tid & 31;
                int r = rp5 + rs;
                if (r >= olo && r <= ohi) {
                    int b = s_base[r + 2];
                    float o = 0.f;
                    if (b < 128) {
                        const int2 dd = *(const int2*)&s_db[r][0];
                        int yb = md5(m5 + 4 + rs);   // (r-1)%5 base
#pragma unroll
                        for (int dy = 0; dy < 3; ++dy) {
                            int j;
                            if (dy == 0)      j = min(max(c + dd.x + 3, 0), 35);
                            else if (dy == 1) j = c + 2;
                            else              j = min(max(c + dd.y + 3, 0), 35);
                            int ds = md5(yb + dy);
                            const float* Dp = &s_D[ds][dy * 3][0];
                            o += Dp[j] + Dp[38 + j + 1] + Dp[76 + j + 2];
                        }
                    }
                    s_out3[f & 1][rs][c] = o + b3s;
                }
            }
        }
        wg_barrier();

        // ===================== G2 =====================
        // CONV1 pair f-1: packed-pair fp32 (float2 oc pairs)
        {
            int r = S + 2 * (f - 1) + rowsub;
            if (f >= 1 && r >= x1lo && r <= x1hi) {
                int b = s_base[r + 2];
                if (b < 128) {
                    int x1b = m5 + rowsub;
                    int sl0 = md5(x1b + 2);   // (r+4)%5
                    int sl1 = md5(x1b + 3);   // r%5
                    int sl2 = md5(x1b + 4);   // (r+1)%5
                    const int2 dd = *(const int2*)&s_db[r][0];
                    float vin[9];
                    {
                        const float* r0 = &s_in[sl0][0];
                        const float* r1 = &s_in[sl1][0];
                        const float* r2 = &s_in[sl2][0];
                        int j0 = min(max(col + dd.x + 3, 0), 35);
                        int j2 = min(max(col + dd.y + 3, 0), 35);
                        vin[0] = r0[j0]; vin[1] = r0[j0 + 1]; vin[2] = r0[j0 + 2];
                        vin[3] = r1[col + 2]; vin[4] = r1[col + 3]; vin[5] = r1[col + 4];
                        vin[6] = r2[j2]; vin[7] = r2[j2 + 1]; vin[8] = r2[j2 + 2];
                    }
                    const fx2* wpp = (const fx2*)w1p + grp * 36;
                    fx2 ap0 = *(const fx2*)(b1 + grp * 8 + 0);
                    fx2 ap1 = *(const fx2*)(b1 + grp * 8 + 2);
                    fx2 ap2 = *(const fx2*)(b1 + grp * 8 + 4);
                    fx2 ap3 = *(const fx2*)(b1 + grp * 8 + 6);
#pragma unroll
                    for (int j = 0; j < 9; ++j) {
                        fx2 vv; vv[0] = vin[j]; vv[1] = vin[j];
                        ap0 = wpp[j]      * vv + ap0;
                        ap1 = wpp[9 + j]  * vv + ap1;
                        ap2 = wpp[18 + j] * vv + ap2;
                        ap3 = wpp[27 + j] * vv + ap3;
                    }
                    const fx2 z2 = {0.f, 0.f};
                    ap0 = __builtin_elementwise_max(ap0, z2);
                    ap1 = __builtin_elementwise_max(ap1, z2);
                    ap2 = __builtin_elementwise_max(ap2, z2);
                    ap3 = __builtin_elementwise_max(ap3, z2);
                    uint4 pk;
                    pk.x = cvt_pk_bf16(ap0[0], ap0[1]);
                    pk.y = cvt_pk_bf16(ap1[0], ap1[1]);
                    pk.z = cvt_pk_bf16(ap2[0], ap2[1]);
                    pk.w = cvt_pk_bf16(ap3[0], ap3[1]);
                    *(uint4*)&s_x1[sl1][(col + 3) * 40 + grp * 8] = pk;
                }
            }

            // CONV3 on pair f-3 (reads s_x2 written in G1(f))
            const int rp3 = S + 2 * (f - 3);
            const bool act3 = (f >= 3) && (rp3 <= x2hi) && (rp3 + 1 >= x2lo);
            if (act3) {
                int rv = grp & 1, nt = grp >> 1;
                const short* bp = &s_x2[rv][(nt * 16 + n) * 72 + (quad << 3)];
                s16x8 bf0 = *(const s16x8*)bp;
                s16x8 bf1 = *(const s16x8*)(bp + 32);
                fx4 a3 = {0.f, 0.f, 0.f, 0.f};
                a3 = __builtin_amdgcn_mfma_f32_16x16x32_bf16(w3f0, bf0, a3, 0, 0, 0);
                a3 = __builtin_amdgcn_mfma_f32_16x16x32_bf16(w3f1, bf1, a3, 0, 0, 0);
                int dslot = md5(m5 + 4 + rv);   // (rp3+rv)%5
#pragma unroll
                for (int e = 0; e < 4; ++e) {
                    int m = (quad << 2) + e;
                    if (m < 9) s_D[dslot][m][3 + nt * 16 + n] = a3[e];
                }
            }
        }
        wg_barrier();
        m5 = md5(m5 + 2);
    }

    if (tid < 200) s_lin[tid] = lacc;
    __syncthreads();
    if (tid < 25) {
        float s = 0.f;
#pragma unroll
        for (int g = 0; g < 8; ++g) s += s_lin[tid * 8 + g];
        patches[pbo * 25 + tid] = s;
    }
}

// ---------------------------------------------------------------------------
// k_img: blocks 0..63 compute y_hat once -> out[0..16383]; blocks 64..93
// zero the s_hat accumulation region.
// ---------------------------------------------------------------------------
__global__ __launch_bounds__(256) void k_img(const float* __restrict__ patches,
                                             const float* __restrict__ linb,
                                             float* __restrict__ out)
{
    const int blk = blockIdx.x, tid = threadIdx.x;
    if (blk < 64) {
        int i = blk * 256 + tid;            // < 16384
        int y = i >> 7, x = i & 127;
        float rec = 0.f;
        if (y < 125 && x < 125) {
            int pp = (y / 5) * 25 + (x / 5);
            int k  = (y % 5) * 5 + (x % 5);
            rec = patches[(2 * pp) * 25 + k] + patches[(2 * pp + 1) * 25 + k]
                + linb[k];
        }
        out[i] = 1.f / (1.f + expf(-rec));
    } else {
        int j = (blk - 64) * 256 + tid;     // < 7680
        if (j < A_DIM * 128) out[128 * 128 + j] = 0.f;
    }
}

// ---------------------------------------------------------------------------
// k_rad: 240 blocks = 60 angles x 4 s-chunks; y_hat L2-resident -> LDS via
// float4; fp32 atomicAdd partials into s_hat.
// ---------------------------------------------------------------------------
__global__ __launch_bounds__(256) void k_rad(const float* __restrict__ yimg,
                                             float* __restrict__ out)
{
    __shared__ float img[128 * 128];
    __shared__ float s_r[2][128];
    const int tid = threadIdx.x;
    const int a   = blockIdx.x >> 2;
    const int cch = blockIdx.x & 3;

#pragma unroll
    for (int j = 0; j < 16; ++j) {
        int idx = j * 256 + tid;            // float4 index < 4096
        ((float4*)img)[idx] = ((const float4*)yimg)[idx];
    }
    __syncthreads();

    const int t  = tid & 127;
    const int ss = tid >> 7;
    double ang = (double)a * (M_PI / 180.0);
    float ct = (float)cos(ang);
    float st = (float)sin(ang);
    const float c = 63.5f;
    float tt = (float)t - c;
    float sum = 0.f;
    int s0 = cch * 32 + ss * 16;
    for (int s = s0; s < s0 + 16; ++s) {
        float sv = (float)s - c;
        float x = c + tt * ct - sv * st;
        float y = c + tt * st + sv * ct;
        float fx = floorf(x), fy = floorf(y);
        int x0 = (int)fx, y0 = (int)fy;
        float wx = x - fx, wy = y - fy;
        bool vx0 = (x0 >= 0) & (x0 < 128), vx1 = (x0 + 1 >= 0) & (x0 + 1 < 128);
        bool vy0 = (y0 >= 0) & (y0 < 128), vy1 = (y0 + 1 >= 0) & (y0 + 1 < 128);
        int xc0 = min(max(x0, 0), 127), xc1 = min(max(x0 + 1, 0), 127);
        int yc0 = min(max(y0, 0), 127), yc1 = min(max(y0 + 1, 0), 127);
        float v00 = (vx0 & vy0) ? img[yc0 * 128 + xc0] : 0.f;
        float v10 = (vx1 & vy0) ? img[yc0 * 128 + xc1] : 0.f;
        float v01 = (vx0 & vy1) ? img[yc1 * 128 + xc0] : 0.f;
        float v11 = (vx1 & vy1) ? img[yc1 * 128 + xc1] : 0.f;
        sum += v00 * (1.f - wx) * (1.f - wy)
             + v10 * wx * (1.f - wy)
             + v01 * (1.f - wx) * wy
             + v11 * wx * wy;
    }
    s_r[ss][t] = sum;
    __syncthreads();
    if (ss == 0)
        atomicAdd(out + 128 * 128 + a * 128 + t, s_r[0][t] + s_r[1][t]);
}

// ---------------------------------------------------------------------------
extern "C" void kernel_launch(void* const* d_in, const int* in_sizes, int n_in,
                              void* d_out, int out_size, void* d_ws, size_t ws_size,
                              hipStream_t stream)
{
    (void)in_sizes; (void)n_in; (void)out_size; (void)ws_size;

    const float* sino  = (const float*)d_in[0];
    const float* w1    = (const float*)d_in[1];
    const float* b1    = (const float*)d_in[2];
    const float* w2    = (const float*)d_in[3];
    const float* b2    = (const float*)d_in[4];
    const float* w3    = (const float*)d_in[5];
    const float* b3    = (const float*)d_in[6];
    const float* lw    = (const float*)d_in[7];
    const float* lb    = (const float*)d_in[8];
    const int*   masks = (const int*)d_in[9];

    float* out = (float*)d_out;

    char* ws = (char*)d_ws;
    float* patches = (float*)ws;                        // 1250*25 fl = 125 KB
    int*   win     = (int*)(ws + 128 * 1024);           // 160 KB
    short* w2a     = (short*)(ws + 288 * 1024);         // 36 KB
    short* w3a     = (short*)(ws + 328 * 1024);         // 2 KB
    int*   actCnt  = (int*)(ws + 332 * 1024);           // 4 B
    int*   actList = (int*)(ws + 332 * 1024 + 64);      // 2.5 KB
    float* w1p     = (float*)(ws + 336 * 1024);         // 1.2 KB (oc pairs)

    k_prep<<<698, 256, 0, stream>>>(masks, w1, w2, w3, win, w2a, w3a, w1p,
                                    patches, actCnt, actList);
    k_pipeline<<<2 * NPATCH, 256, 0, stream>>>(sino, w1p, b1, w2a, b2, w3a, b3,
                                               lw, masks, win, actCnt, actList,
                                               patches);
    k_img<<<94, 256, 0, stream>>>(patches, lb, out);
    k_rad<<<4 * A_DIM, 256, 0, stream>>>(out, out);
}